// Round 8
// baseline (20796.167 us; speedup 1.0000x reference)
//
#include <hip/hip_runtime.h>
#include <hip/hip_bf16.h>
#include <math.h>

#define B_ 64
#define T_ 1024
#define D_ 512
#define H_ 512
#define M_ 256
#define CC 63
#define SS 64
#define NBLK 1024
#define INV_SQRT_2PI 0.3989422804014327f

typedef __attribute__((ext_vector_type(8))) short short8v;

static __device__ __forceinline__ float bf2f(unsigned short u) {
    unsigned int x = ((unsigned int)u) << 16;
    return __uint_as_float(x);
}
static __device__ __forceinline__ unsigned short f2bf(float f) {
    unsigned int x = __float_as_uint(f);
    unsigned int r = (x + 0x7fff + ((x >> 16) & 1)) >> 16;
    return (unsigned short)r;
}
static __device__ __forceinline__ float sigm(float x) {
    return 1.f / (1.f + __expf(-x));
}
static __device__ __forceinline__ float wsum64(float v) {
    for (int o = 32; o > 0; o >>= 1) v += __shfl_xor(v, o, 64);
    return v;
}

// ---- uncached (agent-scope) accessors: ONLY for small same-address mutable data ----
static __device__ __forceinline__ float cload(const float* p) {
    return __hip_atomic_load(p, __ATOMIC_RELAXED, __HIP_MEMORY_SCOPE_AGENT);
}
static __device__ __forceinline__ void cstore(float* p, float v) {
    __hip_atomic_store(p, v, __ATOMIC_RELAXED, __HIP_MEMORY_SCOPE_AGENT);
}
static __device__ __forceinline__ int cloadi(const int* p) {
    return __hip_atomic_load(p, __ATOMIC_RELAXED, __HIP_MEMORY_SCOPE_AGENT);
}
static __device__ __forceinline__ void cstorei(int* p, int v) {
    __hip_atomic_store(p, v, __ATOMIC_RELAXED, __HIP_MEMORY_SCOPE_AGENT);
}
static __device__ __forceinline__ float2 cload2(const float* p) {
    union { unsigned long long u64; float2 f2; } cv;
    cv.u64 = __hip_atomic_load((const unsigned long long*)p, __ATOMIC_RELAXED, __HIP_MEMORY_SCOPE_AGENT);
    return cv.f2;
}

// fence-free tree barrier: 16 groups x 64 blocks; relaxed agent atomics only.
// Mutable cross-phase data is either write-through to FRESH (versioned) addresses
// (safe for plain cached reads) or fully uncached — so no cache fences needed.
static __device__ __forceinline__ void gbar(int* bar, int& epoch) {
    epoch += 1;
    __syncthreads();
    if (threadIdx.x == 0) {
        int gid = blockIdx.x >> 6;
        int v = __hip_atomic_fetch_add(bar + gid * 32, 1, __ATOMIC_RELAXED, __HIP_MEMORY_SCOPE_AGENT);
        if (v == epoch * 64 - 1) {
            int g = __hip_atomic_fetch_add(bar + 1024, 1, __ATOMIC_RELAXED, __HIP_MEMORY_SCOPE_AGENT);
            if (g == epoch * 16 - 1) {
#pragma unroll
                for (int i = 0; i < 16; ++i)
                    __hip_atomic_store(bar + 512 + i * 32, epoch, __ATOMIC_RELAXED, __HIP_MEMORY_SCOPE_AGENT);
            }
        }
        while (__hip_atomic_load(bar + 512 + gid * 32, __ATOMIC_RELAXED, __HIP_MEMORY_SCOPE_AGENT) < epoch)
            __builtin_amdgcn_s_sleep(2);
        asm volatile("" ::: "memory");
    }
    __syncthreads();
}

// ---------------- prologue kernels ----------------

__global__ __launch_bounds__(256) void k_conv(const float* __restrict__ src,
        unsigned short* __restrict__ dst, int n4) {
    int stride = gridDim.x * 256;
    for (int i = blockIdx.x * 256 + threadIdx.x; i < n4; i += stride) {
        float4 v = ((const float4*)src)[i];
        ushort4 o;
        o.x = f2bf(v.x); o.y = f2bf(v.y); o.z = f2bf(v.z); o.w = f2bf(v.w);
        ((ushort4*)dst)[i] = o;
    }
}

// r1-proven f32 tile GEMM with bf16 output: clT[b*256+m][t] = bf16(relu(...))
__global__ __launch_bounds__(256) void k_gemm(const float* __restrict__ Lf,
        const float* __restrict__ psiw, const float* __restrict__ psib,
        unsigned short* __restrict__ clT) {
    __shared__ float At[64 * 65];
    __shared__ float Bt[64 * 65];
    int tid = threadIdx.x;
    int pt = blockIdx.x >> 2;
    int mt = blockIdx.x & 3;
    int p0 = pt * 64, m0 = mt * 64;
    int tp = tid >> 4, tm = tid & 15;
    float acc[4][4] = {{0.f}};
    for (int k0 = 0; k0 < 512; k0 += 64) {
        __syncthreads();
        for (int i = 0; i < 16; ++i) {
            int lidx = i * 256 + tid;
            int r = lidx >> 6, c = lidx & 63;
            At[r * 65 + c] = Lf[(size_t)(p0 + r) * 512 + k0 + c];
            Bt[r * 65 + c] = psiw[(size_t)(m0 + r) * 512 + k0 + c];
        }
        __syncthreads();
        for (int dk = 0; dk < 64; ++dk) {
            float av[4], bv[4];
#pragma unroll
            for (int i = 0; i < 4; ++i) av[i] = At[(4 * tp + i) * 65 + dk];
#pragma unroll
            for (int j = 0; j < 4; ++j) bv[j] = Bt[(4 * tm + j) * 65 + dk];
#pragma unroll
            for (int i = 0; i < 4; ++i)
#pragma unroll
                for (int j = 0; j < 4; ++j)
                    acc[i][j] = fmaf(av[i], bv[j], acc[i][j]);
        }
    }
#pragma unroll
    for (int i = 0; i < 4; ++i) {
        int p = p0 + 4 * tp + i;
        int b = p >> 10, t = p & 1023;
#pragma unroll
        for (int j = 0; j < 4; ++j) {
            int m = m0 + 4 * tm + j;
            float v = fmaxf(acc[i][j] + psib[m], 0.f);
            clT[((size_t)(b * 256 + m)) * 1024 + t] = f2bf(v);
        }
    }
}

// ---------------- persistent mega kernel, 1024 blocks, fence-free + versioned ----------------

__global__ __launch_bounds__(256, 4) void k_mega(
        const unsigned short* __restrict__ Lbf, const float* __restrict__ Lf,
        const float* __restrict__ gt,
        const float* __restrict__ phiw, const float* __restrict__ phib,
        const float* __restrict__ wih0, const float* __restrict__ whh0,
        const float* __restrict__ bih0, const float* __restrict__ bhh0,
        const float* __restrict__ wih1, const float* __restrict__ whh1,
        const float* __restrict__ bih1, const float* __restrict__ bhh1,
        const float* __restrict__ charw, const float* __restrict__ charb,
        const unsigned short* __restrict__ clT,
        float* gtT, float* h0v, float* h1v, float* h1bv,
        float* ctxTv, float* ctxbv, float* energyT, float* vbuf,
        float* logit, int* colZero, int* bar,
        float* preds, float* atts) {
    __shared__ __align__(16) float smem[6464];   // 25.9 KB overlay

    int tid = threadIdx.x, blk = blockIdx.x;
    int epoch = 0;
    int role = blk & 7;
    float c0reg = 0.f, c1reg = 0.f;

    // ---- INIT: version-0 state (write-through), gtT ----
    if (blk < 64) {
        int s0 = blk;
        for (int r = tid; r < CC * 64; r += 256) {
            int k = r >> 6, b = r & 63;
            cstore(&gtT[s0 * (CC * 64) + r], gt[(b * SS + s0) * CC + k]);
        }
    } else if (blk < 192) {
        int idx = (blk - 64) * 256 + tid;
        cstore(&h0v[idx], 0.f);
        cstore(&h1v[idx], 0.f);
        int d = idx >> 6, b = idx & 63;
        float v = Lf[(size_t)b * (T_ * D_) + d];
        cstore(&ctxTv[idx], v);
        cstore(&ctxbv[b * 512 + d], v);
    }
    gbar(bar, epoch);

    for (int s = 0; s < SS; ++s) {
        const float* h0in   = h0v   + (size_t)s * 32768;
        float*       h0out  = h0v   + (size_t)(s + 1) * 32768;
        const float* h1in   = h1v   + (size_t)s * 32768;
        float*       h1out  = h1v   + (size_t)(s + 1) * 32768;
        const float* h1b_prev = h1bv + (size_t)s * 32768;
        float*       h1b_cur  = h1bv + (size_t)(s + 1) * 32768;
        const float* ctxTin = ctxTv + (size_t)s * 32768;
        float*       ctxTout = ctxTv + (size_t)(s + 1) * 32768;
        const float* ctxbin = ctxbv + (size_t)s * 32768;
        float*       ctxbout = ctxbv + (size_t)(s + 1) * 32768;

        // ==== phase A: LSTM0 (role 0) || char-logits(s-1) (role 1) ====
        if (role == 0) {
            int uid = blk >> 3;
            float* xs = smem;                    // [64 k][64 b]
            float* wsm = smem + 4096;            // [16 r][68]
            float* ex = smem + 5184;             // [16 r][64 b]
            int r = tid >> 4, tb = tid & 15;
            float a0 = 0.f, a1 = 0.f, a2 = 0.f, a3 = 0.f;
            for (int kc = 0; kc < 17; ++kc) {
                int k0 = kc * 64;
                __syncthreads();
#pragma unroll
                for (int i = 0; i < 4; ++i) {
                    int e4 = i * 256 + tid;
                    int kk = e4 >> 4, b4 = (e4 & 15) * 4;
                    int k = k0 + kk;
                    float4 v;
                    if (k < 63) {
                        if (s > 0) v = *(const float4*)&gtT[(s - 1) * 4032 + k * 64 + b4];
                        else { float o1 = (k == 0) ? 1.f : 0.f; v = make_float4(o1, o1, o1, o1); }
                    } else if (k < 575)  v = *(const float4*)&ctxTin[(k - 63) * 64 + b4];
                    else if (k < 1087)   v = *(const float4*)&h0in[(k - 575) * 64 + b4];
                    else                 v = make_float4(0.f, 0.f, 0.f, 0.f);
                    *(float4*)&xs[kk * 64 + b4] = v;
                }
#pragma unroll
                for (int i = 0; i < 4; ++i) {
                    int lidx = i * 256 + tid;
                    int rr = lidx >> 6, kk = lidx & 63;
                    int k = k0 + kk;
                    int g2 = rr >> 2, uu = rr & 3;
                    int jj = g2 * 512 + uid * 4 + uu;
                    float w;
                    if (k < 575)       w = wih0[(size_t)jj * 575 + k];
                    else if (k < 1087) w = whh0[(size_t)jj * 512 + (k - 575)];
                    else               w = 0.f;
                    wsm[rr * 68 + kk] = w;
                }
                __syncthreads();
                const float* wsr = &wsm[r * 68];
                const float* xsr = &xs[tb * 4];
#pragma unroll
                for (int kk = 0; kk < 64; ++kk) {
                    float wv = wsr[kk];
                    float4 x4 = *(const float4*)&xsr[kk * 64];
                    a0 = fmaf(wv, x4.x, a0);
                    a1 = fmaf(wv, x4.y, a1);
                    a2 = fmaf(wv, x4.z, a2);
                    a3 = fmaf(wv, x4.w, a3);
                }
            }
            {
                int g2 = r >> 2, uu = r & 3;
                int j = g2 * 512 + (blk >> 3) * 4 + uu;
                float bias = bih0[j] + bhh0[j];
                __syncthreads();
                *(float4*)&ex[r * 64 + tb * 4] =
                    make_float4(a0 + bias, a1 + bias, a2 + bias, a3 + bias);
            }
            __syncthreads();
            {
                int ui = tid >> 6, b = tid & 63;
                float gi = ex[(0 * 4 + ui) * 64 + b];
                float gf = ex[(1 * 4 + ui) * 64 + b];
                float gg = ex[(2 * 4 + ui) * 64 + b];
                float go = ex[(3 * 4 + ui) * 64 + b];
                float cn = sigm(gf) * c0reg + sigm(gi) * tanhf(gg);
                float hn = sigm(go) * tanhf(cn);
                c0reg = cn;
                cstore(&h0out[((blk >> 3) * 4 + ui) * 64 + b], hn);
            }
        } else if (role == 1 && s > 0) {
            int idx = blk >> 3;
            int bcp = idx >> 1, chalf = idx & 1;
            float* xc = smem;                    // 1056 padded
#pragma unroll
            for (int i = 0; i < 2; ++i) {
                int k = (i * 256 + tid) * 2;
                float2 v = (k < 512) ? *(const float2*)&h1b_prev[bcp * 512 + k]
                                     : *(const float2*)&ctxbin[bcp * 512 + (k - 512)];
                int pk = k + (k >> 5);
                xc[pk] = v.x; xc[pk + 1] = v.y;
            }
            __syncthreads();
            int c8 = tid >> 3, kl = tid & 7;
            int c = chalf * 32 + c8;
            float p = 0.f;
            if (c < 63) {
                const float4* cw = (const float4*)&charw[(size_t)c * 1024 + kl * 128];
#pragma unroll
                for (int q = 0; q < 32; ++q) {
                    int k = kl * 128 + q * 4;
                    float4 w4 = cw[q];
                    const float* xp = &xc[k + (k >> 5)];
                    p = fmaf(xp[0], w4.x, p); p = fmaf(xp[1], w4.y, p);
                    p = fmaf(xp[2], w4.z, p); p = fmaf(xp[3], w4.w, p);
                }
            }
            p += __shfl_xor(p, 1, 64); p += __shfl_xor(p, 2, 64); p += __shfl_xor(p, 4, 64);
            if (kl == 0 && c < 63) cstore(&logit[bcp * 64 + c], p + charb[c]);
        }
        gbar(bar, epoch);

        // ==== phase B: LSTM1 (role 2) || preds(s-1) + colZero init (role 3) ====
        if (role == 2) {
            int uid = blk >> 3;
            float* xs = smem;
            float* wsm = smem + 4096;
            float* ex = smem + 5184;
            int r = tid >> 4, tb = tid & 15;
            float a0 = 0.f, a1 = 0.f, a2 = 0.f, a3 = 0.f;
            for (int kc = 0; kc < 16; ++kc) {
                int k0 = kc * 64;
                __syncthreads();
#pragma unroll
                for (int i = 0; i < 4; ++i) {
                    int e4 = i * 256 + tid;
                    int kk = e4 >> 4, b4 = (e4 & 15) * 4;
                    int k = k0 + kk;
                    float4 v = (k < 512) ? *(const float4*)&h0out[k * 64 + b4]
                                         : *(const float4*)&h1in[(k - 512) * 64 + b4];
                    *(float4*)&xs[kk * 64 + b4] = v;
                }
#pragma unroll
                for (int i = 0; i < 4; ++i) {
                    int lidx = i * 256 + tid;
                    int rr = lidx >> 6, kk = lidx & 63;
                    int k = k0 + kk;
                    int g2 = rr >> 2, uu = rr & 3;
                    int jj = g2 * 512 + uid * 4 + uu;
                    float w = (k < 512) ? wih1[(size_t)jj * 512 + k]
                                        : whh1[(size_t)jj * 512 + (k - 512)];
                    wsm[rr * 68 + kk] = w;
                }
                __syncthreads();
                const float* wsr = &wsm[r * 68];
                const float* xsr = &xs[tb * 4];
#pragma unroll
                for (int kk = 0; kk < 64; ++kk) {
                    float wv = wsr[kk];
                    float4 x4 = *(const float4*)&xsr[kk * 64];
                    a0 = fmaf(wv, x4.x, a0);
                    a1 = fmaf(wv, x4.y, a1);
                    a2 = fmaf(wv, x4.z, a2);
                    a3 = fmaf(wv, x4.w, a3);
                }
            }
            {
                int g2 = r >> 2, uu = r & 3;
                int j = g2 * 512 + uid * 4 + uu;
                float bias = bih1[j] + bhh1[j];
                __syncthreads();
                *(float4*)&ex[r * 64 + tb * 4] =
                    make_float4(a0 + bias, a1 + bias, a2 + bias, a3 + bias);
            }
            __syncthreads();
            {
                int ui = tid >> 6, b = tid & 63;
                float gi = ex[(0 * 4 + ui) * 64 + b];
                float gf = ex[(1 * 4 + ui) * 64 + b];
                float gg = ex[(2 * 4 + ui) * 64 + b];
                float go = ex[(3 * 4 + ui) * 64 + b];
                float cn = sigm(gf) * c1reg + sigm(gi) * tanhf(gg);
                float hn = sigm(go) * tanhf(cn);
                c1reg = cn;
                int u = uid * 4 + ui;
                cstore(&h1out[u * 64 + b], hn);
                cstore(&h1b_cur[b * 512 + u], hn);
            }
        } else if (role == 3) {
            int idx = blk >> 3;
            if (idx < 64) {
                if (s > 0 && tid < 64) {
                    int b = idx, c = tid;
                    float lg = (c < 63) ? cload(&logit[b * 64 + c]) : -1e30f;
                    float mx = lg;
                    for (int o = 32; o > 0; o >>= 1) mx = fmaxf(mx, __shfl_xor(mx, o, 64));
                    float ex2 = (c < 63) ? __expf(lg - mx) : 0.f;
                    float sume = wsum64(ex2);
                    if (c < 63)
                        preds[((size_t)(s - 1) * B_ + b) * CC + c] = lg - mx - __logf(sume);
                }
            } else {
                if (tid < 16) cstorei(&colZero[(idx - 64) * 16 + tid], 1);
            }
        }
        gbar(bar, epoch);

        // ==== phase CD: phi (r1-order) + energy bf16 (r1-order), role 4, 128 blocks ====
        if (role == 4) {
            int idx = blk >> 3;                  // 0..127
            int b = idx >> 1, half = idx & 1;
            float* xl = smem;                    // 512
            float* cdl = smem + 512;             // 256
            {
                float2 hv = *(const float2*)&h1b_cur[b * 512 + tid * 2];
                *(float2*)&xl[tid * 2] = hv;
            }
            __syncthreads();
            {
                float a = phib[tid];
                const float4* wr = (const float4*)&phiw[(size_t)tid * 512];
#pragma unroll 8
                for (int q = 0; q < 128; ++q) {
                    float4 w4 = wr[q];
                    const float* xp = &xl[q * 4];
                    a = fmaf(xp[0], w4.x, a); a = fmaf(xp[1], w4.y, a);
                    a = fmaf(xp[2], w4.z, a); a = fmaf(xp[3], w4.w, a);
                }
                cdl[tid] = fmaxf(a, 0.f);
            }
            __syncthreads();
            int t2 = half * 512 + tid * 2;
            float e0 = 0.f, e1 = 0.f;
            const unsigned short* base = clT + ((size_t)(b * 256)) * 1024 + t2;
#pragma unroll 8
            for (int m = 0; m < 256; ++m) {
                unsigned int v = *(const unsigned int*)(base + (size_t)m * 1024);
                float c = cdl[m];
                e0 = fmaf(c, bf2f((unsigned short)(v & 0xffff)), e0);
                e1 = fmaf(c, bf2f((unsigned short)(v >> 16)), e1);
            }
            cstore(&energyT[t2 * 64 + b], e0);
            cstore(&energyT[(t2 + 1) * 64 + b], e1);
            if (e0 != 0.f) cstorei(&colZero[t2], 0);
            if (e1 != 0.f) cstorei(&colZero[t2 + 1], 0);
        }
        gbar(bar, epoch);

        // ==== phase E: copula stats + vals (256 blocks, uncached energyT reads) ====
        if ((blk & 3) == 0) {
            int idx = blk >> 2;
            int* zred = (int*)smem;
            int zacc = cloadi(&colZero[tid]) | cloadi(&colZero[256 + tid])
                     | cloadi(&colZero[512 + tid]) | cloadi(&colZero[768 + tid]);
            zred[tid] = zacc;
            __syncthreads();
            for (int o = 128; o > 0; o >>= 1) {
                if (tid < o) zred[tid] |= zred[tid + o];
                __syncthreads();
            }
            int zf = zred[0];
            int wv = tid >> 6, b = tid & 63;
            int t = idx * 4 + wv;
            float e = cload(&energyT[t * 64 + b]);
            float a = (t > 0) ? cload(&energyT[(t - 1) * 64 + b]) : 0.f;
            float val;
            if (zf) {
                val = e;
            } else {
                float cp;
                if (t >= 1 && t < 1023) {
                    float ma = wsum64(a) * (1.f / 64.f);
                    float mb = wsum64(e) * (1.f / 64.f);
                    float am = a - ma, bm = e - mb;
                    float sab = wsum64(am * bm);
                    float saa = wsum64(am * am);
                    float sbb = wsum64(bm * bm);
                    int aeq = __all(a == e);
                    float r = sab / sqrtf(saa * sbb + 1e-12f);
                    float det = 1.f - r * r;
                    if (det < 0.01f || aeq) cp = 10.f;
                    else {
                        float ds = fmaxf(det, 1e-6f);
                        float quad = r * r * (a * a + e * e) - 2.f * r * a * e;
                        cp = __expf(-0.5f * quad / ds) / sqrtf(ds);
                    }
                } else {
                    cp = 1.f;
                }
                float pdf = __expf(-0.5f * e * e) * INV_SQRT_2PI;
                val = pdf * cp;
            }
            cstore(&vbuf[b * 1024 + t], val);
        }
        gbar(bar, epoch);

        // ==== phase F: softmax + atts + context (1024 blocks: b x 16 d-chunks of 32) ====
        {
            int b = blk >> 4, dq = blk & 15, d0 = dq * 32;
            float* red = smem;
            float* red2 = smem + 256;
            float2 w0 = cload2(&vbuf[b * 1024 + tid * 4]);
            float2 w1 = cload2(&vbuf[b * 1024 + tid * 4 + 2]);
            float4 v4 = make_float4(w0.x, w0.y, w1.x, w1.y);
            float lm = fmaxf(fmaxf(v4.x, v4.y), fmaxf(v4.z, v4.w));
            red[tid] = lm;
            __syncthreads();
            for (int o = 128; o > 0; o >>= 1) {
                if (tid < o) red[tid] = fmaxf(red[tid], red[tid + o]);
                __syncthreads();
            }
            float M = red[0];
            __syncthreads();
            float e0 = __expf(v4.x - M), e1 = __expf(v4.y - M);
            float e2 = __expf(v4.z - M), e3 = __expf(v4.w - M);
            red[tid] = e0 + e1 + e2 + e3;
            __syncthreads();
            for (int o = 128; o > 0; o >>= 1) {
                if (tid < o) red[tid] += red[tid + o];
                __syncthreads();
            }
            float inv = 1.f / red[0];
            float4 a4 = make_float4(e0 * inv, e1 * inv, e2 * inv, e3 * inv);
            if (dq == 0)
                *(float4*)&atts[((size_t)s * B_ + b) * 1024 + tid * 4] = a4;
            __syncthreads();
            int tc = tid >> 2, dg = tid & 3;
            int d8 = d0 + dg * 8;
            float acc[8] = {0.f, 0.f, 0.f, 0.f, 0.f, 0.f, 0.f, 0.f};
            const unsigned short* Lb = Lbf + (size_t)b * 524288 + (size_t)(tc * 16) * 512 + d8;
#pragma unroll
            for (int q = 0; q < 4; ++q) {
                int src = (tc * 4 + q) & 63;
                float av0 = __shfl(a4.x, src, 64);
                float av1 = __shfl(a4.y, src, 64);
                float av2 = __shfl(a4.z, src, 64);
                float av3 = __shfl(a4.w, src, 64);
                float avs[4] = {av0, av1, av2, av3};
#pragma unroll
                for (int e = 0; e < 4; ++e) {
                    float wv2 = avs[e];
                    short8v v = *(const short8v*)(Lb + (size_t)(q * 4 + e) * 512);
                    acc[0] = fmaf(wv2, bf2f((unsigned short)v[0]), acc[0]);
                    acc[1] = fmaf(wv2, bf2f((unsigned short)v[1]), acc[1]);
                    acc[2] = fmaf(wv2, bf2f((unsigned short)v[2]), acc[2]);
                    acc[3] = fmaf(wv2, bf2f((unsigned short)v[3]), acc[3]);
                    acc[4] = fmaf(wv2, bf2f((unsigned short)v[4]), acc[4]);
                    acc[5] = fmaf(wv2, bf2f((unsigned short)v[5]), acc[5]);
                    acc[6] = fmaf(wv2, bf2f((unsigned short)v[6]), acc[6]);
                    acc[7] = fmaf(wv2, bf2f((unsigned short)v[7]), acc[7]);
                }
            }
#pragma unroll
            for (int j = 0; j < 8; ++j) {
                acc[j] += __shfl_xor(acc[j], 4, 64);
                acc[j] += __shfl_xor(acc[j], 8, 64);
                acc[j] += __shfl_xor(acc[j], 16, 64);
                acc[j] += __shfl_xor(acc[j], 32, 64);
            }
            int w = tid >> 6;
            if ((tid & 60) == 0) {
#pragma unroll
                for (int j = 0; j < 8; ++j) red2[w * 32 + dg * 8 + j] = acc[j];
            }
            __syncthreads();
            if (tid < 32) {
                float cv = red2[tid] + red2[32 + tid] + red2[64 + tid] + red2[96 + tid];
                cstore(&ctxTout[(d0 + tid) * 64 + b], cv);
                cstore(&ctxbout[b * 512 + d0 + tid], cv);
            }
        }
        gbar(bar, epoch);
    }

    // ---- tail: char-logits(63) then preds(63) ----
    if (role == 1) {
        int idx = blk >> 3;
        int bcp = idx >> 1, chalf = idx & 1;
        const float* h1b_last = h1bv + (size_t)SS * 32768;
        const float* ctxb_last = ctxbv + (size_t)SS * 32768;
        float* xc = smem;
#pragma unroll
        for (int i = 0; i < 2; ++i) {
            int k = (i * 256 + tid) * 2;
            float2 v = (k < 512) ? *(const float2*)&h1b_last[bcp * 512 + k]
                                 : *(const float2*)&ctxb_last[bcp * 512 + (k - 512)];
            int pk = k + (k >> 5);
            xc[pk] = v.x; xc[pk + 1] = v.y;
        }
        __syncthreads();
        int c8 = tid >> 3, kl = tid & 7;
        int c = chalf * 32 + c8;
        float p = 0.f;
        if (c < 63) {
            const float4* cw = (const float4*)&charw[(size_t)c * 1024 + kl * 128];
#pragma unroll
            for (int q = 0; q < 32; ++q) {
                int k = kl * 128 + q * 4;
                float4 w4 = cw[q];
                const float* xp = &xc[k + (k >> 5)];
                p = fmaf(xp[0], w4.x, p); p = fmaf(xp[1], w4.y, p);
                p = fmaf(xp[2], w4.z, p); p = fmaf(xp[3], w4.w, p);
            }
        }
        p += __shfl_xor(p, 1, 64); p += __shfl_xor(p, 2, 64); p += __shfl_xor(p, 4, 64);
        if (kl == 0 && c < 63) cstore(&logit[bcp * 64 + c], p + charb[c]);
    }
    gbar(bar, epoch);
    if (blk < 64 && tid < 64) {
        int b = blk, c = tid;
        float lg = (c < 63) ? cload(&logit[b * 64 + c]) : -1e30f;
        float mx = lg;
        for (int o = 32; o > 0; o >>= 1) mx = fmaxf(mx, __shfl_xor(mx, o, 64));
        float ex2 = (c < 63) ? __expf(lg - mx) : 0.f;
        float sume = wsum64(ex2);
        if (c < 63)
            preds[((size_t)(SS - 1) * B_ + b) * CC + c] = lg - mx - __logf(sume);
    }
}

extern "C" void kernel_launch(void* const* d_in, const int* in_sizes, int n_in,
                              void* d_out, int out_size, void* d_ws, size_t ws_size,
                              hipStream_t stream) {
    const float* Lf   = (const float*)d_in[0];
    const float* gt   = (const float*)d_in[1];
    const float* phiw = (const float*)d_in[2];
    const float* phib = (const float*)d_in[3];
    const float* psiw = (const float*)d_in[4];
    const float* psib = (const float*)d_in[5];
    const float* wih0 = (const float*)d_in[6];
    const float* whh0 = (const float*)d_in[7];
    const float* bih0 = (const float*)d_in[8];
    const float* bhh0 = (const float*)d_in[9];
    const float* wih1 = (const float*)d_in[10];
    const float* whh1 = (const float*)d_in[11];
    const float* bih1 = (const float*)d_in[12];
    const float* bhh1 = (const float*)d_in[13];
    const float* charw = (const float*)d_in[14];
    const float* charb = (const float*)d_in[15];

    float* preds = (float*)d_out;
    float* atts  = (float*)d_out + (size_t)SS * B_ * CC;

    char* ws = (char*)d_ws;
    size_t off = 0;
    auto alloc = [&](size_t bytes) { size_t o = off; off = (off + bytes + 255) & ~(size_t)255; return o; };
    unsigned short* clT = (unsigned short*)(ws + alloc((size_t)B_ * M_ * T_ * 2));   // bf16
    unsigned short* Lbf = (unsigned short*)(ws + alloc((size_t)B_ * T_ * D_ * 2));
    float* gtT     = (float*)(ws + alloc((size_t)SS * CC * 64 * 4));
    float* h0v     = (float*)(ws + alloc((size_t)(SS + 1) * H_ * B_ * 4));   // versioned
    float* h1v     = (float*)(ws + alloc((size_t)(SS + 1) * H_ * B_ * 4));
    float* h1bv    = (float*)(ws + alloc((size_t)(SS + 1) * H_ * B_ * 4));
    float* ctxTv   = (float*)(ws + alloc((size_t)(SS + 1) * H_ * B_ * 4));
    float* ctxbv   = (float*)(ws + alloc((size_t)(SS + 1) * H_ * B_ * 4));
    float* energyT = (float*)(ws + alloc(B_ * T_ * 4));
    float* vbuf    = (float*)(ws + alloc(B_ * T_ * 4));
    float* logit   = (float*)(ws + alloc(B_ * 64 * 4));
    int* colZero   = (int*)(ws + alloc(1024 * 4));
    int* bar       = (int*)(ws + alloc(2048 * 4));

    hipMemsetAsync(bar, 0, 2048 * 4, stream);
    k_gemm<<<4096, 256, 0, stream>>>(Lf, psiw, psib, clT);
    k_conv<<<2048, 256, 0, stream>>>(Lf, Lbf, (B_ * T_ * D_) / 4);
    k_mega<<<NBLK, 256, 0, stream>>>(Lbf, Lf, gt,
                                     phiw, phib, wih0, whh0, bih0, bhh0,
                                     wih1, whh1, bih1, bhh1, charw, charb,
                                     clT, gtT, h0v, h1v, h1bv,
                                     ctxTv, ctxbv, energyT, vbuf,
                                     logit, colZero, bar, preds, atts);
}

// Round 9
// 9440.416 us; speedup vs baseline: 2.2029x; 2.2029x over previous
//
#include <hip/hip_runtime.h>
#include <hip/hip_bf16.h>
#include <math.h>

#define B_ 64
#define T_ 1024
#define D_ 512
#define H_ 512
#define M_ 256
#define CC 63
#define SS 64
#define INV_SQRT_2PI 0.3989422804014327f

typedef __attribute__((ext_vector_type(8))) short short8v;
typedef __attribute__((ext_vector_type(4))) float f32x4;

static __device__ __forceinline__ float bf2f(unsigned short u) {
    unsigned int x = ((unsigned int)u) << 16;
    return __uint_as_float(x);
}
static __device__ __forceinline__ unsigned short f2bf(float f) {
    unsigned int x = __float_as_uint(f);
    unsigned int r = (x + 0x7fff + ((x >> 16) & 1)) >> 16;
    return (unsigned short)r;
}
static __device__ __forceinline__ float sigm(float x) {
    return 1.f / (1.f + __expf(-x));
}
static __device__ __forceinline__ float wsum64(float v) {
    for (int o = 32; o > 0; o >>= 1) v += __shfl_xor(v, o, 64);
    return v;
}

// ---------------- prologue ----------------

__global__ __launch_bounds__(256) void k_conv(const float* __restrict__ src,
        unsigned short* __restrict__ dst, int n4) {
    int stride = gridDim.x * 256;
    for (int i = blockIdx.x * 256 + threadIdx.x; i < n4; i += stride) {
        float4 v = ((const float4*)src)[i];
        ushort4 o;
        o.x = f2bf(v.x); o.y = f2bf(v.y); o.z = f2bf(v.z); o.w = f2bf(v.w);
        ((ushort4*)dst)[i] = o;
    }
}

// MFMA bf16 GEMM (r2-proven): clT[b*256+m][t] = bf16(relu(Lbf x psibf^T + psib))
__global__ __launch_bounds__(256) void k_gemm_mfma(
        const unsigned short* __restrict__ Abf,
        const unsigned short* __restrict__ Bbf,
        const float* __restrict__ psib,
        unsigned short* __restrict__ clT) {
    __shared__ unsigned short As[64 * 40];
    __shared__ unsigned short Bs[64 * 40];
    __shared__ unsigned short Os[64 * 72];
    int tid = threadIdx.x;
    int p0 = (blockIdx.x >> 2) * 64;
    int m0 = (blockIdx.x & 3) * 64;
    int w = tid >> 6, l = tid & 63;
    int wp = (w & 1) * 32, wm = (w >> 1) * 32;
    f32x4 acc[2][2] = {};
    int srow = tid >> 2, sc = (tid & 3) * 8;
    for (int k0 = 0; k0 < 512; k0 += 32) {
        __syncthreads();
        *(short8v*)&As[srow * 40 + sc] = *(const short8v*)&Abf[(size_t)(p0 + srow) * 512 + k0 + sc];
        *(short8v*)&Bs[srow * 40 + sc] = *(const short8v*)&Bbf[(size_t)(m0 + srow) * 512 + k0 + sc];
        __syncthreads();
        int koff = (l >> 4) * 8;
        int rlo = l & 15;
        short8v a0 = *(short8v*)&As[(wp + rlo) * 40 + koff];
        short8v a1 = *(short8v*)&As[(wp + 16 + rlo) * 40 + koff];
        short8v b0 = *(short8v*)&Bs[(wm + rlo) * 40 + koff];
        short8v b1 = *(short8v*)&Bs[(wm + 16 + rlo) * 40 + koff];
        acc[0][0] = __builtin_amdgcn_mfma_f32_16x16x32_bf16(a0, b0, acc[0][0], 0, 0, 0);
        acc[0][1] = __builtin_amdgcn_mfma_f32_16x16x32_bf16(a0, b1, acc[0][1], 0, 0, 0);
        acc[1][0] = __builtin_amdgcn_mfma_f32_16x16x32_bf16(a1, b0, acc[1][0], 0, 0, 0);
        acc[1][1] = __builtin_amdgcn_mfma_f32_16x16x32_bf16(a1, b1, acc[1][1], 0, 0, 0);
    }
    __syncthreads();
#pragma unroll
    for (int pi = 0; pi < 2; ++pi)
#pragma unroll
        for (int mi = 0; mi < 2; ++mi)
#pragma unroll
            for (int r = 0; r < 4; ++r) {
                int tl = wp + pi * 16 + (l >> 4) * 4 + r;
                int ml = wm + mi * 16 + (l & 15);
                float v = fmaxf(acc[pi][mi][r] + psib[m0 + ml], 0.f);
                Os[ml * 72 + tl] = f2bf(v);
            }
    __syncthreads();
    int b = p0 >> 10, t0 = p0 & 1023;
    int mm = tid >> 2, c16 = (tid & 3) * 16;
    short8v v0 = *(short8v*)&Os[mm * 72 + c16];
    short8v v1 = *(short8v*)&Os[mm * 72 + c16 + 8];
    size_t base = ((size_t)(b * 256 + m0 + mm)) * 1024 + t0 + c16;
    *(short8v*)&clT[base] = v0;
    *(short8v*)&clT[base + 8] = v1;
}

__global__ __launch_bounds__(256) void k_init(const float* __restrict__ Lf,
        const float* __restrict__ gt,
        float* gtT, float* h0a, float* h1a, float* c0, float* c1,
        float* ctxT, float* ctxb) {
    int tid = threadIdx.x, blk = blockIdx.x;
    if (blk < 64) {
        for (int r = tid; r < CC * 64; r += 256) {
            int k = r >> 6, b = r & 63;
            gtT[blk * (CC * 64) + r] = gt[(b * SS + blk) * CC + k];
        }
    } else {
        int idx = (blk - 64) * 256 + tid;
        h0a[idx] = 0.f; h1a[idx] = 0.f; c0[idx] = 0.f; c1[idx] = 0.f;
        int d = idx >> 6, b = idx & 63;
        float v = Lf[(size_t)b * (T_ * D_) + d];
        ctxT[idx] = v;
        ctxb[b * 512 + d] = v;
    }
}

// ---------------- per-step kernels ----------------

// LSTM0: 128 blocks x 4 units (r8 phase-A structure, plain memory)
__global__ __launch_bounds__(256) void k_lstm0(
        int s, const float* __restrict__ gtT, const float* __restrict__ ctxT,
        const float* __restrict__ h0in, float* __restrict__ h0out,
        float* __restrict__ c0,
        const float* __restrict__ wih0, const float* __restrict__ whh0,
        const float* __restrict__ bih0, const float* __restrict__ bhh0,
        int* __restrict__ colZero) {
    __shared__ float xs[4096];
    __shared__ float wsm[16 * 68];
    __shared__ float ex[16 * 64];
    int tid = threadIdx.x, uid = blockIdx.x;
    int r = tid >> 4, tb = tid & 15;
    float a0 = 0.f, a1 = 0.f, a2 = 0.f, a3 = 0.f;
    for (int kc = 0; kc < 17; ++kc) {
        int k0 = kc * 64;
        __syncthreads();
#pragma unroll
        for (int i = 0; i < 4; ++i) {
            int e4 = i * 256 + tid;
            int kk = e4 >> 4, b4 = (e4 & 15) * 4;
            int k = k0 + kk;
            float4 v;
            if (k < 63) {
                if (s > 0) v = *(const float4*)&gtT[(s - 1) * 4032 + k * 64 + b4];
                else { float o1 = (k == 0) ? 1.f : 0.f; v = make_float4(o1, o1, o1, o1); }
            } else if (k < 575)  v = *(const float4*)&ctxT[(k - 63) * 64 + b4];
            else if (k < 1087)   v = *(const float4*)&h0in[(k - 575) * 64 + b4];
            else                 v = make_float4(0.f, 0.f, 0.f, 0.f);
            *(float4*)&xs[kk * 64 + b4] = v;
        }
#pragma unroll
        for (int i = 0; i < 4; ++i) {
            int lidx = i * 256 + tid;
            int rr = lidx >> 6, kk = lidx & 63;
            int k = k0 + kk;
            int g2 = rr >> 2, uu = rr & 3;
            int jj = g2 * 512 + uid * 4 + uu;
            float wv;
            if (k < 575)       wv = wih0[(size_t)jj * 575 + k];
            else if (k < 1087) wv = whh0[(size_t)jj * 512 + (k - 575)];
            else               wv = 0.f;
            wsm[rr * 68 + kk] = wv;
        }
        __syncthreads();
        const float* wsr = &wsm[r * 68];
        const float* xsr = &xs[tb * 4];
#pragma unroll
        for (int kk = 0; kk < 64; ++kk) {
            float wv = wsr[kk];
            float4 x4 = *(const float4*)&xsr[kk * 64];
            a0 = fmaf(wv, x4.x, a0);
            a1 = fmaf(wv, x4.y, a1);
            a2 = fmaf(wv, x4.z, a2);
            a3 = fmaf(wv, x4.w, a3);
        }
    }
    {
        int g2 = r >> 2, uu = r & 3;
        int j = g2 * 512 + uid * 4 + uu;
        float bias = bih0[j] + bhh0[j];
        __syncthreads();
        *(float4*)&ex[r * 64 + tb * 4] =
            make_float4(a0 + bias, a1 + bias, a2 + bias, a3 + bias);
    }
    __syncthreads();
    {
        int ui = tid >> 6, b = tid & 63;
        float gi = ex[(0 * 4 + ui) * 64 + b];
        float gf = ex[(1 * 4 + ui) * 64 + b];
        float gg = ex[(2 * 4 + ui) * 64 + b];
        float go = ex[(3 * 4 + ui) * 64 + b];
        int u = uid * 4 + ui;
        float cv = c0[u * 64 + b];
        float cn = sigm(gf) * cv + sigm(gi) * tanhf(gg);
        float hn = sigm(go) * tanhf(cn);
        c0[u * 64 + b] = cn;
        h0out[u * 64 + b] = hn;
    }
    if (uid == 0) {
        for (int i = tid; i < 1024; i += 256) colZero[i] = 1;
    }
}

// LSTM1: 128 blocks x 4 units
__global__ __launch_bounds__(256) void k_lstm1(
        const float* __restrict__ h0cur, const float* __restrict__ h1in,
        float* __restrict__ h1out, float* __restrict__ c1,
        float* __restrict__ h1bout,
        const float* __restrict__ wih1, const float* __restrict__ whh1,
        const float* __restrict__ bih1, const float* __restrict__ bhh1) {
    __shared__ float xs[4096];
    __shared__ float wsm[16 * 68];
    __shared__ float ex[16 * 64];
    int tid = threadIdx.x, uid = blockIdx.x;
    int r = tid >> 4, tb = tid & 15;
    float a0 = 0.f, a1 = 0.f, a2 = 0.f, a3 = 0.f;
    for (int kc = 0; kc < 16; ++kc) {
        int k0 = kc * 64;
        __syncthreads();
#pragma unroll
        for (int i = 0; i < 4; ++i) {
            int e4 = i * 256 + tid;
            int kk = e4 >> 4, b4 = (e4 & 15) * 4;
            int k = k0 + kk;
            float4 v = (k < 512) ? *(const float4*)&h0cur[k * 64 + b4]
                                 : *(const float4*)&h1in[(k - 512) * 64 + b4];
            *(float4*)&xs[kk * 64 + b4] = v;
        }
#pragma unroll
        for (int i = 0; i < 4; ++i) {
            int lidx = i * 256 + tid;
            int rr = lidx >> 6, kk = lidx & 63;
            int k = k0 + kk;
            int g2 = rr >> 2, uu = rr & 3;
            int jj = g2 * 512 + uid * 4 + uu;
            float wv = (k < 512) ? wih1[(size_t)jj * 512 + k]
                                 : whh1[(size_t)jj * 512 + (k - 512)];
            wsm[rr * 68 + kk] = wv;
        }
        __syncthreads();
        const float* wsr = &wsm[r * 68];
        const float* xsr = &xs[tb * 4];
#pragma unroll
        for (int kk = 0; kk < 64; ++kk) {
            float wv = wsr[kk];
            float4 x4 = *(const float4*)&xsr[kk * 64];
            a0 = fmaf(wv, x4.x, a0);
            a1 = fmaf(wv, x4.y, a1);
            a2 = fmaf(wv, x4.z, a2);
            a3 = fmaf(wv, x4.w, a3);
        }
    }
    {
        int g2 = r >> 2, uu = r & 3;
        int j = g2 * 512 + uid * 4 + uu;
        float bias = bih1[j] + bhh1[j];
        __syncthreads();
        *(float4*)&ex[r * 64 + tb * 4] =
            make_float4(a0 + bias, a1 + bias, a2 + bias, a3 + bias);
    }
    __syncthreads();
    {
        int ui = tid >> 6, b = tid & 63;
        float gi = ex[(0 * 4 + ui) * 64 + b];
        float gf = ex[(1 * 4 + ui) * 64 + b];
        float gg = ex[(2 * 4 + ui) * 64 + b];
        float go = ex[(3 * 4 + ui) * 64 + b];
        int u = uid * 4 + ui;
        float cv = c1[u * 64 + b];
        float cn = sigm(gf) * cv + sigm(gi) * tanhf(gg);
        float hn = sigm(go) * tanhf(cn);
        c1[u * 64 + b] = cn;
        h1out[u * 64 + b] = hn;
        h1bout[b * 512 + u] = hn;
    }
}

// phi + energy (r8/r1 bit-exact chains): 128 blocks = b x 2 halves
__global__ __launch_bounds__(256) void k_energy(
        const float* __restrict__ h1b,
        const float* __restrict__ phiw, const float* __restrict__ phib,
        const unsigned short* __restrict__ clT,
        float* __restrict__ energy_bt, float* __restrict__ energyT,
        int* __restrict__ colZero) {
    __shared__ float xl[512];
    __shared__ float cdl[256];
    int tid = threadIdx.x;
    int b = blockIdx.x >> 1, half = blockIdx.x & 1;
    *(float2*)&xl[tid * 2] = *(const float2*)&h1b[b * 512 + tid * 2];
    __syncthreads();
    {
        float a = phib[tid];
        const float4* wr = (const float4*)&phiw[(size_t)tid * 512];
#pragma unroll 8
        for (int q = 0; q < 128; ++q) {
            float4 w4 = wr[q];
            const float* xp = &xl[q * 4];
            a = fmaf(xp[0], w4.x, a); a = fmaf(xp[1], w4.y, a);
            a = fmaf(xp[2], w4.z, a); a = fmaf(xp[3], w4.w, a);
        }
        cdl[tid] = fmaxf(a, 0.f);
    }
    __syncthreads();
    int t2 = half * 512 + tid * 2;
    float e0 = 0.f, e1 = 0.f;
    const unsigned short* base = clT + ((size_t)(b * 256)) * 1024 + t2;
#pragma unroll 8
    for (int m = 0; m < 256; ++m) {
        unsigned int v = *(const unsigned int*)(base + (size_t)m * 1024);
        float c = cdl[m];
        e0 = fmaf(c, bf2f((unsigned short)(v & 0xffff)), e0);
        e1 = fmaf(c, bf2f((unsigned short)(v >> 16)), e1);
    }
    energyT[t2 * 64 + b] = e0;
    energyT[(t2 + 1) * 64 + b] = e1;
    *(float2*)&energy_bt[b * 1024 + t2] = make_float2(e0, e1);
    if (e0 != 0.f) colZero[t2] = 0;
    if (e1 != 0.f) colZero[t2 + 1] = 0;
}

// copula column stats (r8-E math): 256 blocks x 4 t
__global__ __launch_bounds__(256) void k_cop(
        const float* __restrict__ energyT,
        float* __restrict__ rS, float* __restrict__ dsS, int* __restrict__ badS) {
    int tid = threadIdx.x;
    int wv = tid >> 6, b = tid & 63;
    int t = blockIdx.x * 4 + wv;
    if (t >= 1 && t < 1023) {
        float e = energyT[t * 64 + b];
        float a = energyT[(t - 1) * 64 + b];
        float ma = wsum64(a) * (1.f / 64.f);
        float mb = wsum64(e) * (1.f / 64.f);
        float am = a - ma, bm = e - mb;
        float sab = wsum64(am * bm);
        float saa = wsum64(am * am);
        float sbb = wsum64(bm * bm);
        int aeq = __all(a == e);
        float r = sab / sqrtf(saa * sbb + 1e-12f);
        float det = 1.f - r * r;
        int bad = (det < 0.01f || aeq) ? 1 : 0;
        float ds = fmaxf(det, 1e-6f);
        if (b == 0) { rS[t] = r; dsS[t] = ds; badS[t] = bad; }
    }
}

// vals + softmax + atts (+ charpred/preds for prow): 64 blocks (one per b)
__global__ __launch_bounds__(256) void k_soft(
        int doSM, int s, int prow,
        const float* __restrict__ energy_bt, const int* __restrict__ colZero,
        const float* __restrict__ rS, const float* __restrict__ dsS,
        const int* __restrict__ badS,
        const float* __restrict__ h1bp, const float* __restrict__ ctxb,
        const float* __restrict__ charw, const float* __restrict__ charb,
        float* __restrict__ preds, float* __restrict__ atts,
        float* __restrict__ attbuf) {
    __shared__ float e_l[1024];
    __shared__ float red[256];
    __shared__ int zred[256];
    __shared__ float cpx[1024];
    __shared__ float lgs[64];
    int tid = threadIdx.x, b = blockIdx.x;
    if (doSM) {
        *(float4*)&e_l[tid * 4] = *(const float4*)&energy_bt[b * 1024 + tid * 4];
        int z = colZero[tid] | colZero[256 + tid] | colZero[512 + tid] | colZero[768 + tid];
        zred[tid] = z;
        __syncthreads();
        for (int o = 128; o > 0; o >>= 1) {
            if (tid < o) zred[tid] |= zred[tid + o];
            __syncthreads();
        }
        int zf = zred[0];
        float4 rv = *(const float4*)&rS[tid * 4];
        float4 dv = *(const float4*)&dsS[tid * 4];
        int4 bv = *(const int4*)&badS[tid * 4];
        float rvv[4] = {rv.x, rv.y, rv.z, rv.w};
        float dvv[4] = {dv.x, dv.y, dv.z, dv.w};
        int bvv[4] = {bv.x, bv.y, bv.z, bv.w};
        float vals[4];
#pragma unroll
        for (int i = 0; i < 4; ++i) {
            int t = tid * 4 + i;
            float e = e_l[t];
            if (zf) {
                vals[i] = e;
            } else {
                float cp;
                if (t == 0 || t == 1023) cp = 1.f;
                else if (bvv[i]) cp = 10.f;
                else {
                    float a = e_l[t - 1];
                    float r = rvv[i], ds = dvv[i];
                    float quad = r * r * (a * a + e * e) - 2.f * r * a * e;
                    cp = __expf(-0.5f * quad / ds) / sqrtf(ds);
                }
                vals[i] = __expf(-0.5f * e * e) * INV_SQRT_2PI * cp;
            }
        }
        float lm = fmaxf(fmaxf(vals[0], vals[1]), fmaxf(vals[2], vals[3]));
        red[tid] = lm;
        __syncthreads();
        for (int o = 128; o > 0; o >>= 1) {
            if (tid < o) red[tid] = fmaxf(red[tid], red[tid + o]);
            __syncthreads();
        }
        float M = red[0];
        __syncthreads();
        float e0 = __expf(vals[0] - M), e1 = __expf(vals[1] - M);
        float e2 = __expf(vals[2] - M), e3 = __expf(vals[3] - M);
        red[tid] = e0 + e1 + e2 + e3;
        __syncthreads();
        for (int o = 128; o > 0; o >>= 1) {
            if (tid < o) red[tid] += red[tid + o];
            __syncthreads();
        }
        float inv = 1.f / red[0];
        float4 a4 = make_float4(e0 * inv, e1 * inv, e2 * inv, e3 * inv);
        *(float4*)&attbuf[b * 1024 + tid * 4] = a4;
        *(float4*)&atts[((size_t)s * B_ + b) * 1024 + tid * 4] = a4;
    }
    if (prow >= 0) {
        __syncthreads();
        for (int i = tid; i < 1024; i += 256)
            cpx[i] = (i < 512) ? h1bp[b * 512 + i] : ctxb[b * 512 + (i - 512)];
        __syncthreads();
        int c = tid >> 2, kl = tid & 3;
        float p = 0.f;
        if (c < 63) {
            const float4* cw = (const float4*)&charw[(size_t)c * 1024 + kl * 256];
            const float4* cx = (const float4*)&cpx[kl * 256];
#pragma unroll
            for (int q = 0; q < 64; ++q) {
                float4 w4 = cw[q], x4 = cx[q];
                p = fmaf(x4.x, w4.x, p); p = fmaf(x4.y, w4.y, p);
                p = fmaf(x4.z, w4.z, p); p = fmaf(x4.w, w4.w, p);
            }
        }
        p += __shfl_xor(p, 1, 64); p += __shfl_xor(p, 2, 64);
        if (kl == 0 && c < 63) lgs[c] = p + charb[c];
        if (tid == 0) lgs[63] = -1e30f;
        __syncthreads();
        if (tid < 64) {
            float lg = (tid < 63) ? lgs[tid] : -1e30f;
            float mx = lg;
            for (int o = 32; o > 0; o >>= 1) mx = fmaxf(mx, __shfl_xor(mx, o, 64));
            float ex2 = (tid < 63) ? __expf(lg - mx) : 0.f;
            float sume = wsum64(ex2);
            if (tid < 63)
                preds[((size_t)prow * B_ + b) * CC + tid] = lg - mx - __logf(sume);
        }
    }
}

// context: 512 blocks = b x 8 d-stripes of 64; full-line coalesced Lbf stream
__global__ __launch_bounds__(256) void k_ctx(
        const float* __restrict__ attbuf, const unsigned short* __restrict__ Lbf,
        float* __restrict__ ctxT, float* __restrict__ ctxb) {
    __shared__ float att[1056];
    __shared__ float red2[256];
    int tid = threadIdx.x;
    int b = blockIdx.x >> 3, dq = blockIdx.x & 7, d0 = dq * 64;
    {
        float4 a4 = *(const float4*)&attbuf[b * 1024 + tid * 4];
        int t = tid * 4;
        int pk = t + (t >> 5);
        att[pk] = a4.x; att[pk + 1] = a4.y; att[pk + 2] = a4.z; att[pk + 3] = a4.w;
    }
    __syncthreads();
    int tc = tid >> 3, dg = tid & 7;
    const unsigned short* Lb = Lbf + (size_t)b * 524288 + (size_t)tc * 32 * 512 + d0 + dg * 8;
    float acc[8] = {0.f, 0.f, 0.f, 0.f, 0.f, 0.f, 0.f, 0.f};
#pragma unroll
    for (int i = 0; i < 32; ++i) {
        float wv = att[tc * 33 + i];
        short8v v = *(const short8v*)(Lb + (size_t)i * 512);
        acc[0] = fmaf(wv, bf2f((unsigned short)v[0]), acc[0]);
        acc[1] = fmaf(wv, bf2f((unsigned short)v[1]), acc[1]);
        acc[2] = fmaf(wv, bf2f((unsigned short)v[2]), acc[2]);
        acc[3] = fmaf(wv, bf2f((unsigned short)v[3]), acc[3]);
        acc[4] = fmaf(wv, bf2f((unsigned short)v[4]), acc[4]);
        acc[5] = fmaf(wv, bf2f((unsigned short)v[5]), acc[5]);
        acc[6] = fmaf(wv, bf2f((unsigned short)v[6]), acc[6]);
        acc[7] = fmaf(wv, bf2f((unsigned short)v[7]), acc[7]);
    }
#pragma unroll
    for (int j = 0; j < 8; ++j) {
        acc[j] += __shfl_xor(acc[j], 8, 64);
        acc[j] += __shfl_xor(acc[j], 16, 64);
        acc[j] += __shfl_xor(acc[j], 32, 64);
    }
    int w = tid >> 6;
    if ((tid & 56) == 0) {
#pragma unroll
        for (int j = 0; j < 8; ++j) red2[w * 64 + dg * 8 + j] = acc[j];
    }
    __syncthreads();
    if (tid < 64) {
        float cv = red2[tid] + red2[64 + tid] + red2[128 + tid] + red2[192 + tid];
        ctxT[(d0 + tid) * 64 + b] = cv;
        ctxb[b * 512 + d0 + tid] = cv;
    }
}

extern "C" void kernel_launch(void* const* d_in, const int* in_sizes, int n_in,
                              void* d_out, int out_size, void* d_ws, size_t ws_size,
                              hipStream_t stream) {
    const float* Lf   = (const float*)d_in[0];
    const float* gt   = (const float*)d_in[1];
    const float* phiw = (const float*)d_in[2];
    const float* phib = (const float*)d_in[3];
    const float* psiw = (const float*)d_in[4];
    const float* psib = (const float*)d_in[5];
    const float* wih0 = (const float*)d_in[6];
    const float* whh0 = (const float*)d_in[7];
    const float* bih0 = (const float*)d_in[8];
    const float* bhh0 = (const float*)d_in[9];
    const float* wih1 = (const float*)d_in[10];
    const float* whh1 = (const float*)d_in[11];
    const float* bih1 = (const float*)d_in[12];
    const float* bhh1 = (const float*)d_in[13];
    const float* charw = (const float*)d_in[14];
    const float* charb = (const float*)d_in[15];

    float* preds = (float*)d_out;
    float* atts  = (float*)d_out + (size_t)SS * B_ * CC;

    char* ws = (char*)d_ws;
    size_t off = 0;
    auto alloc = [&](size_t bytes) { size_t o = off; off = (off + bytes + 255) & ~(size_t)255; return o; };
    unsigned short* clT = (unsigned short*)(ws + alloc((size_t)B_ * M_ * T_ * 2));
    unsigned short* Lbf = (unsigned short*)(ws + alloc((size_t)B_ * T_ * D_ * 2));
    unsigned short* psibf = (unsigned short*)(ws + alloc((size_t)M_ * D_ * 2));
    float* gtT      = (float*)(ws + alloc((size_t)SS * CC * 64 * 4));
    float* h0p0     = (float*)(ws + alloc(H_ * B_ * 4));
    float* h0p1     = (float*)(ws + alloc(H_ * B_ * 4));
    float* h1p0     = (float*)(ws + alloc(H_ * B_ * 4));
    float* h1p1     = (float*)(ws + alloc(H_ * B_ * 4));
    float* hb0      = (float*)(ws + alloc(H_ * B_ * 4));
    float* hb1      = (float*)(ws + alloc(H_ * B_ * 4));
    float* c0       = (float*)(ws + alloc(H_ * B_ * 4));
    float* c1       = (float*)(ws + alloc(H_ * B_ * 4));
    float* ctxT     = (float*)(ws + alloc(H_ * B_ * 4));
    float* ctxb     = (float*)(ws + alloc(H_ * B_ * 4));
    float* energy_bt = (float*)(ws + alloc(B_ * T_ * 4));
    float* energyT   = (float*)(ws + alloc(B_ * T_ * 4));
    float* rS       = (float*)(ws + alloc(T_ * 4));
    float* dsS      = (float*)(ws + alloc(T_ * 4));
    int* badS       = (int*)(ws + alloc(T_ * 4));
    int* colZero    = (int*)(ws + alloc(T_ * 4));
    float* attbuf   = (float*)(ws + alloc(B_ * T_ * 4));

    k_conv<<<2048, 256, 0, stream>>>(Lf, Lbf, (B_ * T_ * D_) / 4);
    k_conv<<<128, 256, 0, stream>>>(psiw, psibf, (M_ * D_) / 4);
    k_gemm_mfma<<<4096, 256, 0, stream>>>(Lbf, psibf, psib, clT);
    k_init<<<192, 256, 0, stream>>>(Lf, gt, gtT, h0p0, h1p0, c0, c1, ctxT, ctxb);

    float* h0p[2] = {h0p0, h0p1};
    float* h1p[2] = {h1p0, h1p1};
    float* hb[2]  = {hb0, hb1};
    for (int s = 0; s < SS; ++s) {
        int pi = s & 1, po = pi ^ 1;
        k_lstm0<<<128, 256, 0, stream>>>(s, gtT, ctxT, h0p[pi], h0p[po], c0,
                                         wih0, whh0, bih0, bhh0, colZero);
        k_lstm1<<<128, 256, 0, stream>>>(h0p[po], h1p[pi], h1p[po], c1, hb[pi],
                                         wih1, whh1, bih1, bhh1);
        k_energy<<<128, 256, 0, stream>>>(hb[pi], phiw, phib, clT,
                                          energy_bt, energyT, colZero);
        k_cop<<<256, 256, 0, stream>>>(energyT, rS, dsS, badS);
        k_soft<<<64, 256, 0, stream>>>(1, s, s - 1, energy_bt, colZero, rS, dsS, badS,
                                       hb[pi ^ 1], ctxb, charw, charb,
                                       preds, atts, attbuf);
        k_ctx<<<512, 256, 0, stream>>>(attbuf, Lbf, ctxT, ctxb);
    }
    // tail: charpred + preds for step 63 (h1b of step 63 = hb[63&1] = hb[1])
    k_soft<<<64, 256, 0, stream>>>(0, SS - 1, SS - 1, energy_bt, colZero, rS, dsS, badS,
                                   hb[1], ctxb, charw, charb, preds, atts, attbuf);
}